// Round 3
// baseline (1622.659 us; speedup 1.0000x reference)
//
#include <hip/hip_runtime.h>
#include <hip/hip_bf16.h>
#include <cstdint>

using bf16 = __hip_bfloat16;
typedef __attribute__((ext_vector_type(8))) short short8;
typedef __attribute__((ext_vector_type(4))) short short4v;
typedef __attribute__((ext_vector_type(4))) float floatx4;

#define DEVINL __device__ __forceinline__

DEVINL short bfbits(float v) { return __builtin_bit_cast(short, __float2bfloat16(v)); }

// Load 8 contiguous elements starting at element offset `off` (multiple of 8),
// as bf16 bits. AF32=1: source is float32, convert. AF32=0: source is bf16.
template<int AF32> DEVINL short8 load8(const void* p, size_t off) {
  short8 r;
  if constexpr (AF32) {
    const float* f = (const float*)p + off;
    floatx4 lo = *(const floatx4*)f;
    floatx4 hi = *(const floatx4*)(f + 4);
#pragma unroll
    for (int i = 0; i < 4; i++) { r[i] = bfbits(lo[i]); r[4 + i] = bfbits(hi[i]); }
  } else {
    r = *(const short8*)((const bf16*)p + off);
  }
  return r;
}

template<int ACT> DEVINL float activate(float v) {
  if constexpr (ACT == 1) return v > 0.f ? v : 0.25f * v;            // leaky_relu(0.25)
  else if constexpr (ACT == 2) return v > 0.f ? v : __expf(v) - 1.f; // elu
  else return v;
}

// C[M,N] = A[M,K] * B[N,K]^T (+bias[col]) (+act).  f32 accum, MFMA bf16.
// AF32: A is float32 (converted during staging).  B is always bf16.
// OF32: store C as float32 (else bf16).
// TRANS=1 (bf16 out only): store C^T at out[col*ldo+row] for later use as B operand.
// Grid: (N/128, M/128), block 256 (4 waves), tile 128x128, BK=64.
template<int ACT, int TRANS, int BIAS, int AF32, int OF32>
__global__ __launch_bounds__(256, 2)
void gemm_bt(const void* __restrict__ A, int lda,
             const bf16* __restrict__ B, int ldb,
             const float* __restrict__ bias,
             void* __restrict__ out, int ldo, int K)
{
  __shared__ bf16 At[128 * 64];
  __shared__ bf16 Bt[128 * 64];
  const int t = threadIdx.x;
  const int wave = t >> 6, lane = t & 63;
  const int mBase = blockIdx.y * 128, nBase = blockIdx.x * 128;
  const int wm = (wave >> 1) * 64, wn = (wave & 1) * 64;
  const int q = lane >> 4, lm = lane & 15;

  floatx4 acc[4][4];
#pragma unroll
  for (int i = 0; i < 4; i++)
#pragma unroll
    for (int j = 0; j < 4; j++) acc[i][j] = (floatx4){0.f, 0.f, 0.f, 0.f};

  for (int kb = 0; kb < K; kb += 64) {
    short8 av[4], bv[4];
#pragma unroll
    for (int i = 0; i < 4; i++) {
      int c = i * 256 + t;                       // c in [0,1024): row=c>>3, col8=c&7
      av[i] = load8<AF32>(A, (size_t)(mBase + (c >> 3)) * lda + kb + ((c & 7) << 3));
      bv[i] = load8<0>(B, (size_t)(nBase + (c >> 3)) * ldb + kb + ((c & 7) << 3));
    }
    __syncthreads();                             // previous iteration's LDS readers done
#pragma unroll
    for (int i = 0; i < 4; i++) {
      int c = i * 256 + t;
      *(short8*)&At[c * 8] = av[i];
      *(short8*)&Bt[c * 8] = bv[i];
    }
    __syncthreads();                             // tiles visible to all waves
#pragma unroll
    for (int ks = 0; ks < 64; ks += 32) {
      short8 af[4], bfr[4];
#pragma unroll
      for (int i = 0; i < 4; i++)
        af[i] = *(const short8*)&At[(wm + i * 16 + lm) * 64 + ks + q * 8];
#pragma unroll
      for (int j = 0; j < 4; j++)
        bfr[j] = *(const short8*)&Bt[(wn + j * 16 + lm) * 64 + ks + q * 8];
#pragma unroll
      for (int i = 0; i < 4; i++)
#pragma unroll
        for (int j = 0; j < 4; j++)
          acc[i][j] = __builtin_amdgcn_mfma_f32_16x16x32_bf16(af[i], bfr[j], acc[i][j], 0, 0, 0);
    }
  }

#pragma unroll
  for (int i = 0; i < 4; i++) {
#pragma unroll
    for (int j = 0; j < 4; j++) {
      const int col = nBase + wn + j * 16 + lm;
      float bv2 = 0.f;
      if constexpr (BIAS) bv2 = bias[col];
      if constexpr (TRANS) {
        short4v pk;
#pragma unroll
        for (int r = 0; r < 4; r++)
          pk[r] = bfbits(activate<ACT>(acc[i][j][r] + bv2));
        const int row = mBase + wm + i * 16 + q * 4;  // 4 consecutive rows contiguous in C^T
        *(short4v*)&((bf16*)out)[(size_t)col * ldo + row] = pk;
      } else {
#pragma unroll
        for (int r = 0; r < 4; r++) {
          const int row = mBase + wm + i * 16 + q * 4 + r;
          float v = activate<ACT>(acc[i][j][r] + bv2);
          if constexpr (OF32) ((float*)out)[(size_t)row * ldo + col] = v;
          else ((bf16*)out)[(size_t)row * ldo + col] = __float2bfloat16(v);
        }
      }
    }
  }
}

// S = A[4096,256] * B[4096,256]^T (A,B bf16); accumulates Rsum[i] += sum_j exp(2*S_ij)
// and (COLS) Csum[j] += sum_i exp(2*S_ij).  Grid (32,32).
template<int COLS>
__global__ __launch_bounds__(256, 2)
void sim_bt(const bf16* __restrict__ A, const bf16* __restrict__ B,
            float* __restrict__ Rsum, float* __restrict__ Csum)
{
  __shared__ bf16 At[128 * 64];
  __shared__ bf16 Bt[128 * 64];
  const int t = threadIdx.x;
  const int wave = t >> 6, lane = t & 63;
  const int mBase = blockIdx.y * 128, nBase = blockIdx.x * 128;
  const int wm = (wave >> 1) * 64, wn = (wave & 1) * 64;
  const int q = lane >> 4, lm = lane & 15;

  floatx4 acc[4][4];
#pragma unroll
  for (int i = 0; i < 4; i++)
#pragma unroll
    for (int j = 0; j < 4; j++) acc[i][j] = (floatx4){0.f, 0.f, 0.f, 0.f};

  for (int kb = 0; kb < 256; kb += 64) {
    short8 av[4], bv[4];
#pragma unroll
    for (int i = 0; i < 4; i++) {
      int c = i * 256 + t;
      av[i] = *(const short8*)(A + (size_t)(mBase + (c >> 3)) * 256 + kb + ((c & 7) << 3));
      bv[i] = *(const short8*)(B + (size_t)(nBase + (c >> 3)) * 256 + kb + ((c & 7) << 3));
    }
    __syncthreads();
#pragma unroll
    for (int i = 0; i < 4; i++) {
      int c = i * 256 + t;
      *(short8*)&At[c * 8] = av[i];
      *(short8*)&Bt[c * 8] = bv[i];
    }
    __syncthreads();
#pragma unroll
    for (int ks = 0; ks < 64; ks += 32) {
      short8 af[4], bfr[4];
#pragma unroll
      for (int i = 0; i < 4; i++)
        af[i] = *(const short8*)&At[(wm + i * 16 + lm) * 64 + ks + q * 8];
#pragma unroll
      for (int j = 0; j < 4; j++)
        bfr[j] = *(const short8*)&Bt[(wn + j * 16 + lm) * 64 + ks + q * 8];
#pragma unroll
      for (int i = 0; i < 4; i++)
#pragma unroll
        for (int j = 0; j < 4; j++)
          acc[i][j] = __builtin_amdgcn_mfma_f32_16x16x32_bf16(af[i], bfr[j], acc[i][j], 0, 0, 0);
    }
  }

  float rs[4][4];
  float cs[4];
#pragma unroll
  for (int i = 0; i < 4; i++) { cs[i] = 0.f;
#pragma unroll
    for (int r = 0; r < 4; r++) rs[i][r] = 0.f; }

#pragma unroll
  for (int i = 0; i < 4; i++)
#pragma unroll
    for (int j = 0; j < 4; j++)
#pragma unroll
      for (int r = 0; r < 4; r++) {
        float e = __expf(2.f * acc[i][j][r]);   // 1/TAU = 2
        rs[i][r] += e;
        if constexpr (COLS) cs[j] += e;
      }

#pragma unroll
  for (int i = 0; i < 4; i++)
#pragma unroll
    for (int r = 0; r < 4; r++) {
      float v = rs[i][r];
      v += __shfl_xor(v, 1); v += __shfl_xor(v, 2);
      v += __shfl_xor(v, 4); v += __shfl_xor(v, 8);
      if (lm == 0) atomicAdd(&Rsum[mBase + wm + i * 16 + q * 4 + r], v);
    }
  if constexpr (COLS) {
#pragma unroll
    for (int j = 0; j < 4; j++) {
      float v = cs[j];
      v += __shfl_xor(v, 16); v += __shfl_xor(v, 32);
      if (lane < 16) atomicAdd(&Csum[nBase + wn + j * 16 + lane], v);
    }
  }
}

// out[C,R] = bf16(in[R,C]^T), in is float32. 32x32 LDS tiles, dims multiples of 32.
__global__ void transpose_f32_bf16(const float* __restrict__ in, bf16* __restrict__ out, int R, int C)
{
  __shared__ float tile[32][33];
  const int bx = blockIdx.x * 32;
  const int by = blockIdx.y * 32;
  const int tx = threadIdx.x & 31, ty = threadIdx.x >> 5;
#pragma unroll
  for (int s = 0; s < 4; s++) {
    int r = ty + s * 8;
    tile[r][tx] = in[(size_t)(by + r) * C + bx + tx];
  }
  __syncthreads();
#pragma unroll
  for (int s = 0; s < 4; s++) {
    int r = ty + s * 8;
    out[(size_t)(bx + r) * R + by + tx] = __float2bfloat16(tile[tx][r]);
  }
}

__global__ void zero_f32(float* __restrict__ p, int n)
{
  int i = blockIdx.x * blockDim.x + threadIdx.x;
  if (i < n) p[i] = 0.f;
}

// one wave per row: n = h / max(||h||, 1e-12), rows of 256 (bf16 in/out)
__global__ void norm_rows(const bf16* __restrict__ h, bf16* __restrict__ n)
{
  const int row = blockIdx.x * 4 + (threadIdx.x >> 6);
  const int lane = threadIdx.x & 63;
  float v[4]; float ss = 0.f;
#pragma unroll
  for (int j = 0; j < 4; j++) {
    v[j] = __bfloat162float(h[(size_t)row * 256 + lane * 4 + j]);
    ss += v[j] * v[j];
  }
  for (int m = 1; m < 64; m <<= 1) ss += __shfl_xor(ss, m);
  const float s = 1.0f / fmaxf(sqrtf(ss), 1e-12f);
#pragma unroll
  for (int j = 0; j < 4; j++)
    n[(size_t)row * 256 + lane * 4 + j] = __float2bfloat16(v[j] * s);
}

// one wave per row: diagonals from direct dots; accumulate weighted loss
__global__ void loss_partial(const bf16* __restrict__ n1, const bf16* __restrict__ n2,
                             const float* __restrict__ R11, const float* __restrict__ R12,
                             const float* __restrict__ R22, const float* __restrict__ C12,
                             float* __restrict__ lossAcc)
{
  const int row = blockIdx.x * 4 + (threadIdx.x >> 6);
  const int lane = threadIdx.x & 63;
  float d12 = 0.f, d11 = 0.f, d22 = 0.f;
#pragma unroll
  for (int j = 0; j < 4; j++) {
    float a = __bfloat162float(n1[(size_t)row * 256 + lane * 4 + j]);
    float b = __bfloat162float(n2[(size_t)row * 256 + lane * 4 + j]);
    d12 += a * b; d11 += a * a; d22 += b * b;
  }
  for (int m = 1; m < 64; m <<= 1) {
    d12 += __shfl_xor(d12, m); d11 += __shfl_xor(d11, m); d22 += __shfl_xor(d22, m);
  }
  if (lane == 0) {
    float a1 = fmaxf(R11[row] + R12[row] - __expf(2.f * d11), 1e-20f);
    float a2 = fmaxf(R22[row] + C12[row] - __expf(2.f * d22), 1e-20f);
    float l1 = logf(a1) - 2.f * d12;
    float l2 = logf(a2) - 2.f * d12;
    atomicAdd(lossAcc, 0.8f * l1 + 0.2f * l2);
  }
}

__global__ void finalize_loss(const float* __restrict__ lossAcc, float* __restrict__ out)
{
  if (threadIdx.x == 0) out[0] = *lossAcc;
}

extern "C" void kernel_launch(void* const* d_in, const int* in_sizes, int n_in,
                              void* d_out, int out_size, void* d_ws, size_t ws_size,
                              hipStream_t stream)
{
  (void)in_sizes; (void)n_in; (void)out_size; (void)ws_size;
  // All inputs are float32 per the reference (jnp.float32 throughout).
  const float* x1   = (const float*)d_in[0];
  const float* adj1 = (const float*)d_in[1];
  const float* x2   = (const float*)d_in[2];
  const float* adj2 = (const float*)d_in[3];
  const float* W1a  = (const float*)d_in[4];  const float* b1a = (const float*)d_in[5];
  const float* W1b  = (const float*)d_in[6];  const float* b1b = (const float*)d_in[7];
  const float* W2a  = (const float*)d_in[8];  const float* b2a = (const float*)d_in[9];
  const float* W2b  = (const float*)d_in[10]; const float* b2b = (const float*)d_in[11];
  const float* fc1w = (const float*)d_in[12]; const float* fc1b = (const float*)d_in[13];
  const float* fc11w= (const float*)d_in[14]; const float* fc11b= (const float*)d_in[15];
  const float* fc12w= (const float*)d_in[16]; const float* fc12b= (const float*)d_in[17];
  const float* fc2w = (const float*)d_in[18]; const float* fc2b = (const float*)d_in[19];
  const float* fc3w = (const float*)d_in[20]; const float* fc3b = (const float*)d_in[21];

  float* z1 = (float*)d_out;                        // [4096,2048] f32
  float* z2 = z1 + (size_t)4096 * 2048;             // [4096,2048] f32
  float* lossOut = z1 + (size_t)2 * 4096 * 2048;    // [1] f32

  // Workspace layout (~26.1 MiB, bf16 internals, aggressively aliased):
  //  [0,8M):   WT (weight^T bf16); later P2(4M@+0), P3(2M@+4M), P4(4M@+0), Hp(2M@+4M)
  //  [8M,16M): TT ((x@W+b)^T bf16 [1024,4096]); later P1 (8M)
  //  [16M,20M): fc1T   [20M,21M): fc11T
  //  [21M,+256K): fc12T  [+256K,+512K): fc2T  [+512K,+768K): fc3T
  //  [22M,24M): n1   [24M,26M): n2   [26M,+64K+4): R11,R12,R22,C12,lossAcc
  char* w = (char*)d_ws;
  bf16* WT    = (bf16*)(w);
  bf16* TT    = (bf16*)(w + (8u  << 20));
  bf16* P1    = (bf16*)(w + (8u  << 20));         // aliases TT (TT dead before P1 written)
  bf16* P2    = (bf16*)(w);                       // aliases WT (WT dead before P2 written)
  bf16* P3    = (bf16*)(w + (4u  << 20));
  bf16* P4    = (bf16*)(w);                       // over P2 (P2 dead)
  bf16* Hp    = (bf16*)(w + (4u  << 20));         // over P3 (P3 dead)
  bf16* fc1T  = (bf16*)(w + (16u << 20));
  bf16* fc11T = (bf16*)(w + (20u << 20));
  bf16* fc12T = (bf16*)(w + (21u << 20));
  bf16* fc2T  = (bf16*)(w + (21u << 20) + (256u << 10));
  bf16* fc3T  = (bf16*)(w + (21u << 20) + (512u << 10));
  bf16* n1    = (bf16*)(w + (22u << 20));
  bf16* n2    = (bf16*)(w + (24u << 20));
  float* R11  = (float*)(w + (26u << 20));
  float* R12  = R11 + 4096;
  float* R22  = R12 + 4096;
  float* C12  = R22 + 4096;
  float* lossAcc = C12 + 4096;

  dim3 blk(256);

  zero_f32<<<dim3(65), blk, 0, stream>>>(R11, 4 * 4096 + 1);

  // projection-head weight transposes f32 -> bf16 (shared by both views)
  transpose_f32_bf16<<<dim3(32, 64), blk, 0, stream>>>(fc1w,  fc1T,  2048, 1024);
  transpose_f32_bf16<<<dim3(16, 32), blk, 0, stream>>>(fc11w, fc11T, 1024, 512);
  transpose_f32_bf16<<<dim3(8, 16),  blk, 0, stream>>>(fc12w, fc12T, 512, 256);
  transpose_f32_bf16<<<dim3(16, 8),  blk, 0, stream>>>(fc2w,  fc2T,  256, 512);
  transpose_f32_bf16<<<dim3(8, 16),  blk, 0, stream>>>(fc3w,  fc3T,  512, 256);

  for (int v = 0; v < 2; v++) {
    const float* x  = v ? x2 : x1;
    const float* G  = v ? adj2 : adj1;
    const float* Wa = v ? W2a : W1a;  const float* ba = v ? b2a : b1a;
    const float* Wb = v ? W2b : W1b;  const float* bb = v ? b2b : b1b;
    float* z  = v ? z2 : z1;
    bf16* nv = v ? n2 : n1;

    // h1 = leaky(G @ (x @ Wa + ba))
    transpose_f32_bf16<<<dim3(32, 128), blk, 0, stream>>>(Wa, WT, 4096, 1024);
    gemm_bt<0, 1, 1, 1, 0><<<dim3(8, 32), blk, 0, stream>>>(x, 4096, WT, 4096, ba, TT, 4096, 4096);
    gemm_bt<1, 0, 0, 1, 1><<<dim3(8, 32), blk, 0, stream>>>(G, 4096, TT, 4096, nullptr, z, 2048, 4096);
    // h2 = leaky(G @ (h1 @ Wb + bb))
    transpose_f32_bf16<<<dim3(32, 32), blk, 0, stream>>>(Wb, WT, 1024, 1024);
    gemm_bt<0, 1, 1, 1, 0><<<dim3(8, 32), blk, 0, stream>>>(z, 2048, WT, 1024, bb, TT, 4096, 1024);
    gemm_bt<1, 0, 0, 1, 1><<<dim3(8, 32), blk, 0, stream>>>(G, 4096, TT, 4096, nullptr, z + 1024, 2048, 4096);

    // projection head on z=[h1|h2] (f32 in d_out)
    gemm_bt<2, 0, 1, 1, 0><<<dim3(8, 32), blk, 0, stream>>>(z,  2048, fc1T,  2048, fc1b,  P1, 1024, 2048);
    gemm_bt<2, 0, 1, 0, 0><<<dim3(4, 32), blk, 0, stream>>>(P1, 1024, fc11T, 1024, fc11b, P2, 512, 1024);
    gemm_bt<2, 0, 1, 0, 0><<<dim3(2, 32), blk, 0, stream>>>(P2, 512,  fc12T, 512,  fc12b, P3, 256, 512);
    gemm_bt<2, 0, 1, 0, 0><<<dim3(4, 32), blk, 0, stream>>>(P3, 256,  fc2T,  256,  fc2b,  P4, 512, 256);
    gemm_bt<0, 0, 1, 0, 0><<<dim3(2, 32), blk, 0, stream>>>(P4, 512,  fc3T,  512,  fc3b,  Hp, 256, 512);
    norm_rows<<<dim3(1024), blk, 0, stream>>>(Hp, nv);
  }

  // exp-sum reductions of the three similarity matrices (never materialized)
  sim_bt<0><<<dim3(32, 32), blk, 0, stream>>>(n1, n1, R11, nullptr);
  sim_bt<0><<<dim3(32, 32), blk, 0, stream>>>(n2, n2, R22, nullptr);
  sim_bt<1><<<dim3(32, 32), blk, 0, stream>>>(n1, n2, R12, C12);

  loss_partial<<<dim3(1024), blk, 0, stream>>>(n1, n2, R11, R12, R22, C12, lossAcc);
  finalize_loss<<<dim3(1), dim3(64), 0, stream>>>(lossAcc, lossOut);
}

// Round 4
// 987.302 us; speedup vs baseline: 1.6435x; 1.6435x over previous
//
#include <hip/hip_runtime.h>
#include <hip/hip_bf16.h>
#include <cstdint>

using bf16 = __hip_bfloat16;
typedef __attribute__((ext_vector_type(8))) short short8;
typedef __attribute__((ext_vector_type(4))) short short4v;
typedef __attribute__((ext_vector_type(4))) float floatx4;

#define DEVINL __device__ __forceinline__

DEVINL short bfbits(float v) { return __builtin_bit_cast(short, __float2bfloat16(v)); }

template<int ACT> DEVINL float activate(float v) {
  if constexpr (ACT == 1) return v > 0.f ? v : 0.25f * v;            // leaky_relu(0.25)
  else if constexpr (ACT == 2) return v > 0.f ? v : __expf(v) - 1.f; // elu
  else return v;
}

// C[M,N] = A[M,K] * B[N,K]^T (+bias[col]) (+act).  f32 accum, MFMA bf16.
// blockIdx.z selects view (A1/B1/... vs A2/B2/...), fusing two independent GEMMs.
// AF32: A is float32 (converted at LDS-write). OF32: out is float32.
// TRANS: store C^T (bf16) at out[col*ldo+row]. DUAL (with OF32): also store bf16 C to outB.
// Register-prefetch software pipeline: tile k+1 global loads issued before tile-k MFMA.
template<int ACT, int TRANS, int BIAS, int AF32, int OF32, int DUAL>
__global__ __launch_bounds__(256, 2)
void gemm_bt(const void* __restrict__ A1, const void* __restrict__ A2, int lda,
             const bf16* __restrict__ B1, const bf16* __restrict__ B2, int ldb,
             const float* __restrict__ bias1, const float* __restrict__ bias2,
             void* __restrict__ out1, void* __restrict__ out2,
             bf16* __restrict__ outB1, bf16* __restrict__ outB2,
             int ldo, int K)
{
  const int vz = blockIdx.z;
  const void* A = vz ? A2 : A1;
  const bf16* B = vz ? B2 : B1;
  const float* bias = vz ? bias2 : bias1;
  void* out = vz ? out2 : out1;
  bf16* outB = vz ? outB2 : outB1;

  __shared__ bf16 At[128 * 64];
  __shared__ bf16 Bt[128 * 64];
  const int t = threadIdx.x;
  const int wave = t >> 6, lane = t & 63;
  const int mBase = blockIdx.y * 128, nBase = blockIdx.x * 128;
  const int wm = (wave >> 1) * 64, wn = (wave & 1) * 64;
  const int q = lane >> 4, lm = lane & 15;

  floatx4 acc[4][4];
#pragma unroll
  for (int i = 0; i < 4; i++)
#pragma unroll
    for (int j = 0; j < 4; j++) acc[i][j] = (floatx4){0.f, 0.f, 0.f, 0.f};

  // staging registers (raw; converted at LDS-write time)
  floatx4 apl[4], aph[4];   // AF32 path
  short8  apb[4];           // bf16 path
  short8  bpb[4];

  auto LA = [&](int kb) {
#pragma unroll
    for (int i = 0; i < 4; i++) {
      int c = i * 256 + t;
      size_t off = (size_t)(mBase + (c >> 3)) * lda + kb + ((c & 7) << 3);
      if constexpr (AF32) {
        const float* f = (const float*)A + off;
        apl[i] = *(const floatx4*)f;
        aph[i] = *(const floatx4*)(f + 4);
      } else {
        apb[i] = *(const short8*)((const bf16*)A + off);
      }
    }
  };
  auto LB = [&](int kb) {
#pragma unroll
    for (int i = 0; i < 4; i++) {
      int c = i * 256 + t;
      bpb[i] = *(const short8*)(B + (size_t)(nBase + (c >> 3)) * ldb + kb + ((c & 7) << 3));
    }
  };

  LA(0); LB(0);
  for (int kb = 0; kb < K; kb += 64) {
    __syncthreads();                  // previous iteration's LDS readers done
#pragma unroll
    for (int i = 0; i < 4; i++) {
      int c = i * 256 + t;
      short8 r;
      if constexpr (AF32) {
#pragma unroll
        for (int j = 0; j < 4; j++) { r[j] = bfbits(apl[i][j]); r[4 + j] = bfbits(aph[i][j]); }
      } else {
        r = apb[i];
      }
      *(short8*)&At[c * 8] = r;
      *(short8*)&Bt[c * 8] = bpb[i];
    }
    __syncthreads();                  // tiles visible
    if (kb + 64 < K) { LA(kb + 64); LB(kb + 64); }  // prefetch overlaps MFMA below
#pragma unroll
    for (int ks = 0; ks < 64; ks += 32) {
      short8 af[4], bfr[4];
#pragma unroll
      for (int i = 0; i < 4; i++)
        af[i] = *(const short8*)&At[(wm + i * 16 + lm) * 64 + ks + q * 8];
#pragma unroll
      for (int j = 0; j < 4; j++)
        bfr[j] = *(const short8*)&Bt[(wn + j * 16 + lm) * 64 + ks + q * 8];
#pragma unroll
      for (int i = 0; i < 4; i++)
#pragma unroll
        for (int j = 0; j < 4; j++)
          acc[i][j] = __builtin_amdgcn_mfma_f32_16x16x32_bf16(af[i], bfr[j], acc[i][j], 0, 0, 0);
    }
  }

#pragma unroll
  for (int i = 0; i < 4; i++) {
#pragma unroll
    for (int j = 0; j < 4; j++) {
      const int col = nBase + wn + j * 16 + lm;
      float bv2 = 0.f;
      if constexpr (BIAS) bv2 = bias[col];
      if constexpr (TRANS) {
        short4v pk;
#pragma unroll
        for (int r = 0; r < 4; r++)
          pk[r] = bfbits(activate<ACT>(acc[i][j][r] + bv2));
        const int row = mBase + wm + i * 16 + q * 4;
        *(short4v*)&((bf16*)out)[(size_t)col * ldo + row] = pk;
      } else {
#pragma unroll
        for (int r = 0; r < 4; r++) {
          const int row = mBase + wm + i * 16 + q * 4 + r;
          float v = activate<ACT>(acc[i][j][r] + bv2);
          if constexpr (OF32) ((float*)out)[(size_t)row * ldo + col] = v;
          else ((bf16*)out)[(size_t)row * ldo + col] = __float2bfloat16(v);
          if constexpr (DUAL) outB[(size_t)row * ldo + col] = __float2bfloat16(v);
        }
      }
    }
  }
}

// Fused 3-way sim reduction: blockIdx.z = 0:(n1,n1->R11) 1:(n2,n2->R22) 2:(n1,n2->R12,C12).
// S = A*B^T over K=256; accumulates Rsum[i] += sum_j exp(2*S_ij), Csum[j] += sum_i exp(2*S_ij).
__global__ __launch_bounds__(256, 2)
void sim3(const bf16* __restrict__ n1, const bf16* __restrict__ n2,
          float* __restrict__ R11, float* __restrict__ R22,
          float* __restrict__ R12, float* __restrict__ C12)
{
  const bf16 *A, *B; float *Rs, *Cs;
  if (blockIdx.z == 0)      { A = n1; B = n1; Rs = R11; Cs = nullptr; }
  else if (blockIdx.z == 1) { A = n2; B = n2; Rs = R22; Cs = nullptr; }
  else                      { A = n1; B = n2; Rs = R12; Cs = C12; }

  __shared__ bf16 At[128 * 64];
  __shared__ bf16 Bt[128 * 64];
  const int t = threadIdx.x;
  const int wave = t >> 6, lane = t & 63;
  const int mBase = blockIdx.y * 128, nBase = blockIdx.x * 128;
  const int wm = (wave >> 1) * 64, wn = (wave & 1) * 64;
  const int q = lane >> 4, lm = lane & 15;

  floatx4 acc[4][4];
#pragma unroll
  for (int i = 0; i < 4; i++)
#pragma unroll
    for (int j = 0; j < 4; j++) acc[i][j] = (floatx4){0.f, 0.f, 0.f, 0.f};

  short8 apb[4], bpb[4];
  auto LD = [&](int kb) {
#pragma unroll
    for (int i = 0; i < 4; i++) {
      int c = i * 256 + t;
      apb[i] = *(const short8*)(A + (size_t)(mBase + (c >> 3)) * 256 + kb + ((c & 7) << 3));
      bpb[i] = *(const short8*)(B + (size_t)(nBase + (c >> 3)) * 256 + kb + ((c & 7) << 3));
    }
  };

  LD(0);
  for (int kb = 0; kb < 256; kb += 64) {
    __syncthreads();
#pragma unroll
    for (int i = 0; i < 4; i++) {
      int c = i * 256 + t;
      *(short8*)&At[c * 8] = apb[i];
      *(short8*)&Bt[c * 8] = bpb[i];
    }
    __syncthreads();
    if (kb + 64 < 256) LD(kb + 64);
#pragma unroll
    for (int ks = 0; ks < 64; ks += 32) {
      short8 af[4], bfr[4];
#pragma unroll
      for (int i = 0; i < 4; i++)
        af[i] = *(const short8*)&At[(wm + i * 16 + lm) * 64 + ks + q * 8];
#pragma unroll
      for (int j = 0; j < 4; j++)
        bfr[j] = *(const short8*)&Bt[(wn + j * 16 + lm) * 64 + ks + q * 8];
#pragma unroll
      for (int i = 0; i < 4; i++)
#pragma unroll
        for (int j = 0; j < 4; j++)
          acc[i][j] = __builtin_amdgcn_mfma_f32_16x16x32_bf16(af[i], bfr[j], acc[i][j], 0, 0, 0);
    }
  }

  float rs[4][4], cs[4];
#pragma unroll
  for (int i = 0; i < 4; i++) { cs[i] = 0.f;
#pragma unroll
    for (int r = 0; r < 4; r++) rs[i][r] = 0.f; }

#pragma unroll
  for (int i = 0; i < 4; i++)
#pragma unroll
    for (int j = 0; j < 4; j++)
#pragma unroll
      for (int r = 0; r < 4; r++) {
        float e = __expf(2.f * acc[i][j][r]);   // 1/TAU = 2
        rs[i][r] += e;
        cs[j] += e;
      }

#pragma unroll
  for (int i = 0; i < 4; i++)
#pragma unroll
    for (int r = 0; r < 4; r++) {
      float v = rs[i][r];
      v += __shfl_xor(v, 1); v += __shfl_xor(v, 2);
      v += __shfl_xor(v, 4); v += __shfl_xor(v, 8);
      if (lm == 0) atomicAdd(&Rs[mBase + wm + i * 16 + q * 4 + r], v);
    }
  if (Cs) {
#pragma unroll
    for (int j = 0; j < 4; j++) {
      float v = cs[j];
      v += __shfl_xor(v, 16); v += __shfl_xor(v, 32);
      if (lane < 16) atomicAdd(&Cs[nBase + wn + j * 16 + lane], v);
    }
  }
}

// out[C,R] = bf16(in[R,C]^T), f32 in. blockIdx.z selects the (in,out) pair.
__global__ void transpose2_f32_bf16(const float* __restrict__ in1, const float* __restrict__ in2,
                                    bf16* __restrict__ out1, bf16* __restrict__ out2, int R, int C)
{
  const float* in = blockIdx.z ? in2 : in1;
  bf16* out = blockIdx.z ? out2 : out1;
  __shared__ float tile[32][33];
  const int bx = blockIdx.x * 32;
  const int by = blockIdx.y * 32;
  const int tx = threadIdx.x & 31, ty = threadIdx.x >> 5;
#pragma unroll
  for (int s = 0; s < 4; s++) {
    int r = ty + s * 8;
    tile[r][tx] = in[(size_t)(by + r) * C + bx + tx];
  }
  __syncthreads();
#pragma unroll
  for (int s = 0; s < 4; s++) {
    int r = ty + s * 8;
    out[(size_t)(bx + r) * R + by + tx] = __float2bfloat16(tile[tx][r]);
  }
}

__global__ void zero_f32(float* __restrict__ p, int n)
{
  int i = blockIdx.x * blockDim.x + threadIdx.x;
  if (i < n) p[i] = 0.f;
}

// one wave per row: n = h / max(||h||, 1e-12), rows of 256; z selects view
__global__ void norm_rows2(const bf16* __restrict__ h1, const bf16* __restrict__ h2,
                           bf16* __restrict__ o1, bf16* __restrict__ o2)
{
  const bf16* h = blockIdx.z ? h2 : h1;
  bf16* o = blockIdx.z ? o2 : o1;
  const int row = blockIdx.x * 4 + (threadIdx.x >> 6);
  const int lane = threadIdx.x & 63;
  float v[4]; float ss = 0.f;
#pragma unroll
  for (int j = 0; j < 4; j++) {
    v[j] = __bfloat162float(h[(size_t)row * 256 + lane * 4 + j]);
    ss += v[j] * v[j];
  }
  for (int m = 1; m < 64; m <<= 1) ss += __shfl_xor(ss, m);
  const float s = 1.0f / fmaxf(sqrtf(ss), 1e-12f);
#pragma unroll
  for (int j = 0; j < 4; j++)
    o[(size_t)row * 256 + lane * 4 + j] = __float2bfloat16(v[j] * s);
}

__global__ void loss_partial(const bf16* __restrict__ n1, const bf16* __restrict__ n2,
                             const float* __restrict__ R11, const float* __restrict__ R12,
                             const float* __restrict__ R22, const float* __restrict__ C12,
                             float* __restrict__ lossAcc)
{
  const int row = blockIdx.x * 4 + (threadIdx.x >> 6);
  const int lane = threadIdx.x & 63;
  float d12 = 0.f, d11 = 0.f, d22 = 0.f;
#pragma unroll
  for (int j = 0; j < 4; j++) {
    float a = __bfloat162float(n1[(size_t)row * 256 + lane * 4 + j]);
    float b = __bfloat162float(n2[(size_t)row * 256 + lane * 4 + j]);
    d12 += a * b; d11 += a * a; d22 += b * b;
  }
  for (int m = 1; m < 64; m <<= 1) {
    d12 += __shfl_xor(d12, m); d11 += __shfl_xor(d11, m); d22 += __shfl_xor(d22, m);
  }
  if (lane == 0) {
    float a1 = fmaxf(R11[row] + R12[row] - __expf(2.f * d11), 1e-20f);
    float a2 = fmaxf(R22[row] + C12[row] - __expf(2.f * d22), 1e-20f);
    float l1 = logf(a1) - 2.f * d12;
    float l2 = logf(a2) - 2.f * d12;
    atomicAdd(lossAcc, 0.8f * l1 + 0.2f * l2);
  }
}

__global__ void finalize_loss(const float* __restrict__ lossAcc, float* __restrict__ out)
{
  if (threadIdx.x == 0) out[0] = *lossAcc;
}

extern "C" void kernel_launch(void* const* d_in, const int* in_sizes, int n_in,
                              void* d_out, int out_size, void* d_ws, size_t ws_size,
                              hipStream_t stream)
{
  (void)in_sizes; (void)n_in; (void)out_size; (void)ws_size;
  const float* x1   = (const float*)d_in[0];
  const float* adj1 = (const float*)d_in[1];
  const float* x2   = (const float*)d_in[2];
  const float* adj2 = (const float*)d_in[3];
  const float* W1a  = (const float*)d_in[4];  const float* b1a = (const float*)d_in[5];
  const float* W1b  = (const float*)d_in[6];  const float* b1b = (const float*)d_in[7];
  const float* W2a  = (const float*)d_in[8];  const float* b2a = (const float*)d_in[9];
  const float* W2b  = (const float*)d_in[10]; const float* b2b = (const float*)d_in[11];
  const float* fc1w = (const float*)d_in[12]; const float* fc1b = (const float*)d_in[13];
  const float* fc11w= (const float*)d_in[14]; const float* fc11b= (const float*)d_in[15];
  const float* fc12w= (const float*)d_in[16]; const float* fc12b= (const float*)d_in[17];
  const float* fc2w = (const float*)d_in[18]; const float* fc2b = (const float*)d_in[19];
  const float* fc3w = (const float*)d_in[20]; const float* fc3b = (const float*)d_in[21];

  float* z1 = (float*)d_out;                        // [4096,2048] f32
  float* z2 = z1 + (size_t)4096 * 2048;
  float* lossOut = z1 + (size_t)2 * 4096 * 2048;    // [1]

  // Workspace (~70 MiB, aliased):
  //  [0,16M):  WT1/WT2 (weight^T per view); later P1_1@0,P1_2@8M; then P4_2@0,Hp1@4M,Hp2@6M,n1@8M,n2@10M
  //  [16,32M): TT1@16,TT2@24; later P2_1@16,P2_2@20,P3_1@24,P3_2@26,P4_1@28
  //  [32,64M): zB1@32, zB2@48 (bf16 copies of z)
  //  [64,70M): fc1T@64(4M), fc11T@68(1M), fc12T@69, fc2T@69.25, fc3T@69.5, sums@69.75
  const size_t MB = 1u << 20;
  char* w = (char*)d_ws;
  bf16* WT1  = (bf16*)(w);
  bf16* WT2  = (bf16*)(w + 8 * MB);
  bf16* TT1  = (bf16*)(w + 16 * MB);
  bf16* TT2  = (bf16*)(w + 24 * MB);
  bf16* zB1  = (bf16*)(w + 32 * MB);
  bf16* zB2  = (bf16*)(w + 48 * MB);
  bf16* fc1T = (bf16*)(w + 64 * MB);
  bf16* fc11T= (bf16*)(w + 68 * MB);
  bf16* fc12T= (bf16*)(w + 69 * MB);
  bf16* fc2T = (bf16*)(w + 69 * MB + 256 * 1024);
  bf16* fc3T = (bf16*)(w + 69 * MB + 512 * 1024);
  float* R11 = (float*)(w + 69 * MB + 768 * 1024);
  float* R12 = R11 + 4096;
  float* R22 = R12 + 4096;
  float* C12 = R22 + 4096;
  float* lossAcc = C12 + 4096;
  // projection-chain aliases
  bf16* P1_1 = (bf16*)(w);
  bf16* P1_2 = (bf16*)(w + 8 * MB);
  bf16* P2_1 = (bf16*)(w + 16 * MB);
  bf16* P2_2 = (bf16*)(w + 20 * MB);
  bf16* P3_1 = (bf16*)(w + 24 * MB);
  bf16* P3_2 = (bf16*)(w + 26 * MB);
  bf16* P4_1 = (bf16*)(w + 28 * MB);
  bf16* P4_2 = (bf16*)(w);
  bf16* Hp1  = (bf16*)(w + 4 * MB);
  bf16* Hp2  = (bf16*)(w + 6 * MB);
  bf16* n1   = (bf16*)(w + 8 * MB);
  bf16* n2   = (bf16*)(w + 10 * MB);

  dim3 blk(256);

  zero_f32<<<dim3(65), blk, 0, stream>>>(R11, 4 * 4096 + 1);

  // projection-head weight transposes (shared by both views; z=1)
  transpose2_f32_bf16<<<dim3(32, 64, 1), blk, 0, stream>>>(fc1w, fc1w, fc1T, fc1T, 2048, 1024);
  transpose2_f32_bf16<<<dim3(16, 32, 1), blk, 0, stream>>>(fc11w, fc11w, fc11T, fc11T, 1024, 512);
  transpose2_f32_bf16<<<dim3(8, 16, 1),  blk, 0, stream>>>(fc12w, fc12w, fc12T, fc12T, 512, 256);
  transpose2_f32_bf16<<<dim3(16, 8, 1),  blk, 0, stream>>>(fc2w, fc2w, fc2T, fc2T, 256, 512);
  transpose2_f32_bf16<<<dim3(8, 16, 1),  blk, 0, stream>>>(fc3w, fc3w, fc3T, fc3T, 512, 256);

  // h1 = leaky(G @ (x @ Wa + ba)) — both views fused per launch
  transpose2_f32_bf16<<<dim3(32, 128, 2), blk, 0, stream>>>(W1a, W2a, WT1, WT2, 4096, 1024);
  gemm_bt<0, 1, 1, 1, 0, 0><<<dim3(8, 32, 2), blk, 0, stream>>>(
      x1, x2, 4096, WT1, WT2, 4096, b1a, b2a, TT1, TT2, nullptr, nullptr, 4096, 4096);
  gemm_bt<1, 0, 0, 1, 1, 1><<<dim3(8, 32, 2), blk, 0, stream>>>(
      adj1, adj2, 4096, TT1, TT2, 4096, nullptr, nullptr, z1, z2, zB1, zB2, 2048, 4096);
  // h2 = leaky(G @ (h1 @ Wb + bb))
  transpose2_f32_bf16<<<dim3(32, 32, 2), blk, 0, stream>>>(W1b, W2b, WT1, WT2, 1024, 1024);
  gemm_bt<0, 1, 1, 0, 0, 0><<<dim3(8, 32, 2), blk, 0, stream>>>(
      zB1, zB2, 2048, WT1, WT2, 1024, b1b, b2b, TT1, TT2, nullptr, nullptr, 4096, 1024);
  gemm_bt<1, 0, 0, 1, 1, 1><<<dim3(8, 32, 2), blk, 0, stream>>>(
      adj1, adj2, 4096, TT1, TT2, 4096, nullptr, nullptr, z1 + 1024, z2 + 1024, zB1 + 1024, zB2 + 1024, 2048, 4096);

  // projection head (weights shared across views)
  gemm_bt<2, 0, 1, 0, 0, 0><<<dim3(8, 32, 2), blk, 0, stream>>>(
      zB1, zB2, 2048, fc1T, fc1T, 2048, fc1b, fc1b, P1_1, P1_2, nullptr, nullptr, 1024, 2048);
  gemm_bt<2, 0, 1, 0, 0, 0><<<dim3(4, 32, 2), blk, 0, stream>>>(
      P1_1, P1_2, 1024, fc11T, fc11T, 1024, fc11b, fc11b, P2_1, P2_2, nullptr, nullptr, 512, 1024);
  gemm_bt<2, 0, 1, 0, 0, 0><<<dim3(2, 32, 2), blk, 0, stream>>>(
      P2_1, P2_2, 512, fc12T, fc12T, 512, fc12b, fc12b, P3_1, P3_2, nullptr, nullptr, 256, 512);
  gemm_bt<2, 0, 1, 0, 0, 0><<<dim3(4, 32, 2), blk, 0, stream>>>(
      P3_1, P3_2, 256, fc2T, fc2T, 256, fc2b, fc2b, P4_1, P4_2, nullptr, nullptr, 512, 256);
  gemm_bt<0, 0, 1, 0, 0, 0><<<dim3(2, 32, 2), blk, 0, stream>>>(
      P4_1, P4_2, 512, fc3T, fc3T, 512, fc3b, fc3b, Hp1, Hp2, nullptr, nullptr, 256, 512);
  norm_rows2<<<dim3(1024, 1, 2), blk, 0, stream>>>(Hp1, Hp2, n1, n2);

  // fused exp-sum reductions of the three similarity matrices
  sim3<<<dim3(32, 32, 3), blk, 0, stream>>>(n1, n2, R11, R22, R12, C12);

  loss_partial<<<dim3(1024), blk, 0, stream>>>(n1, n2, R11, R12, R22, C12, lossAcc);
  finalize_loss<<<dim3(1), dim3(64), 0, stream>>>(lossAcc, lossOut);
}